// Round 11
// baseline (173.346 us; speedup 1.0000x reference)
//
#include <hip/hip_runtime.h>
#include <hip/hip_fp16.h>
#include <math.h>

// f(x) = tanh-MLP(x), 1->16->32->32->16->3, per scalar element.
// R11: ONE fused kernel. Blocks 0..511 build the 3x2048 fp16-pair table
// (wave-per-entry, neuron-per-lane, 4-way ILP accumulators) into d_ws and
// bump a device-scope counter; all 1536 blocks spin on the counter, then
// stage the table to LDS and run the streaming lerp (nontemporal stores).
// Grid = 1536 = exactly 6 blocks/CU (24KB LDS, __launch_bounds__(256,6))
// -> all blocks co-resident -> spin is deadlock-free. Counter reset per call
// via 4-byte hipMemsetAsync (graph-capturable).

#define TN 2048
#define XLO (-10.0f)
#define XHI (10.0f)
#define NBUILD 512

typedef float f32x4 __attribute__((ext_vector_type(4)));

__device__ __forceinline__ float fast_tanh(float x) {
    float t = __builtin_amdgcn_exp2f(x * 2.885390081777927f);
    return 1.0f - 2.0f * __builtin_amdgcn_rcpf(t + 1.0f);
}

__global__ __launch_bounds__(256, 6) void fused_nn(
    const float* __restrict__ W0, const float* __restrict__ b0,
    const float* __restrict__ W1, const float* __restrict__ b1,
    const float* __restrict__ W2, const float* __restrict__ b2,
    const float* __restrict__ W3, const float* __restrict__ b3,
    const float* __restrict__ W4, const float* __restrict__ b4,
    unsigned* __restrict__ tab_g, unsigned* __restrict__ cnt,
    const float* __restrict__ x, float4* __restrict__ out4, unsigned n_out4)
{
    // 24KB LDS union: phase1 weights (2212 f32) / phase2 table (3*TN u32)
    __shared__ __align__(16) unsigned smem[3 * TN];
    const int t = threadIdx.x;
    const int b = blockIdx.x;

    if (b < NBUILD) {
        float* w = (float*)smem;
        float4* w4 = (float4*)w;
        // float4 weight staging (segments 16B-aligned in this layout)
        if (t < 4)   w4[t]       = ((const float4*)W0)[t];
        if (t < 4)   w4[4 + t]   = ((const float4*)b0)[t];
        if (t < 128) w4[8 + t]   = ((const float4*)W1)[t];
        if (t < 8)   w4[136 + t] = ((const float4*)b1)[t];
        w4[144 + t] = ((const float4*)W2)[t];
        if (t < 8)   w4[400 + t] = ((const float4*)b2)[t];
        if (t < 128) w4[408 + t] = ((const float4*)W3)[t];
        if (t < 4)   w4[536 + t] = ((const float4*)b3)[t];
        if (t < 12)  w4[540 + t] = ((const float4*)W4)[t];
        if (t < 3)   w[2208 + t] = b4[t];
        __syncthreads();

        const int wave = t >> 6;
        const int half = (t >> 5) & 1;
        const int sub  = t & 31;
        const int s16  = (sub < 15) ? sub : 15;
        const int e    = b * 4 + wave;
        const int p    = min(e + half, TN - 1);

        const float h = (XHI - XLO) / (float)(TN - 1);
        const float xx = XLO + (float)p * h;

        float act = fast_tanh(fmaf(xx, w[s16], w[16 + s16]));
        {
            float acc0 = w[544 + sub], acc1 = 0.f, acc2 = 0.f, acc3 = 0.f;
            #pragma unroll
            for (int k = 0; k < 16; k += 4) {
                float a0 = __shfl(act, k + 0, 32);
                float a1 = __shfl(act, k + 1, 32);
                float a2 = __shfl(act, k + 2, 32);
                float a3 = __shfl(act, k + 3, 32);
                acc0 = fmaf(a0, w[32 + (k + 0) * 32 + sub], acc0);
                acc1 = fmaf(a1, w[32 + (k + 1) * 32 + sub], acc1);
                acc2 = fmaf(a2, w[32 + (k + 2) * 32 + sub], acc2);
                acc3 = fmaf(a3, w[32 + (k + 3) * 32 + sub], acc3);
            }
            act = fast_tanh((acc0 + acc1) + (acc2 + acc3));
        }
        {
            float acc0 = w[1600 + sub], acc1 = 0.f, acc2 = 0.f, acc3 = 0.f;
            #pragma unroll
            for (int k = 0; k < 32; k += 4) {
                float a0 = __shfl(act, k + 0, 32);
                float a1 = __shfl(act, k + 1, 32);
                float a2 = __shfl(act, k + 2, 32);
                float a3 = __shfl(act, k + 3, 32);
                acc0 = fmaf(a0, w[576 + (k + 0) * 32 + sub], acc0);
                acc1 = fmaf(a1, w[576 + (k + 1) * 32 + sub], acc1);
                acc2 = fmaf(a2, w[576 + (k + 2) * 32 + sub], acc2);
                acc3 = fmaf(a3, w[576 + (k + 3) * 32 + sub], acc3);
            }
            act = fast_tanh((acc0 + acc1) + (acc2 + acc3));
        }
        {
            float acc0 = w[2144 + s16], acc1 = 0.f, acc2 = 0.f, acc3 = 0.f;
            #pragma unroll
            for (int k = 0; k < 32; k += 4) {
                float a0 = __shfl(act, k + 0, 32);
                float a1 = __shfl(act, k + 1, 32);
                float a2 = __shfl(act, k + 2, 32);
                float a3 = __shfl(act, k + 3, 32);
                acc0 = fmaf(a0, w[1632 + (k + 0) * 16 + s16], acc0);
                acc1 = fmaf(a1, w[1632 + (k + 1) * 16 + s16], acc1);
                acc2 = fmaf(a2, w[1632 + (k + 2) * 16 + s16], acc2);
                acc3 = fmaf(a3, w[1632 + (k + 3) * 16 + s16], acc3);
            }
            act = fast_tanh((acc0 + acc1) + (acc2 + acc3));
        }
        float o0 = w[2208], o1 = w[2209], o2 = w[2210];
        #pragma unroll
        for (int k = 0; k < 16; ++k) {
            float ak = __shfl(act, k, 32);
            o0 = fmaf(ak, w[2160 + k * 3 + 0], o0);
            o1 = fmaf(ak, w[2160 + k * 3 + 1], o1);
            o2 = fmaf(ak, w[2160 + k * 3 + 2], o2);
        }
        o0 = fast_tanh(o0); o1 = fast_tanh(o1); o2 = fast_tanh(o2);

        float h0 = __shfl(o0, 32, 64);
        float h1 = __shfl(o1, 32, 64);
        float h2 = __shfl(o2, 32, 64);

        if ((t & 63) == 0) {
            __half2 p0 = __floats2half2_rn(o0, h0);
            __half2 p1 = __floats2half2_rn(o1, h1);
            __half2 p2 = __floats2half2_rn(o2, h2);
            tab_g[         e] = *reinterpret_cast<unsigned*>(&p0);
            tab_g[TN     + e] = *reinterpret_cast<unsigned*>(&p1);
            tab_g[2 * TN + e] = *reinterpret_cast<unsigned*>(&p2);
        }
        __syncthreads();                 // all waves done with w[] and writes
        __threadfence();                 // release table writes (device scope)
        if (t == 0) atomicAdd(cnt, 1u);
    }

    // ---- spin until all NBUILD builder blocks have published ----
    if (t == 0) {
        while (atomicAdd(cnt, 0u) < NBUILD) {
            __builtin_amdgcn_s_sleep(32);
        }
    }
    __syncthreads();
    __threadfence();                     // acquire

    // ---- phase 2: table -> LDS, streaming lerp ----
    {
        uint4* dst = (uint4*)smem;
        const uint4* src = (const uint4*)tab_g;
        for (int i = t; i < 3 * TN / 4; i += 256) dst[i] = src[i];
    }
    __syncthreads();
    const unsigned* t0 = smem;
    const unsigned* t1 = smem + TN;
    const unsigned* t2 = smem + 2 * TN;

    const float inv_h = (float)(TN - 1) / (XHI - XLO);
    unsigned stride = gridDim.x * 256u;
    for (unsigned g = b * 256u + t; g < n_out4; g += stride) {
        unsigned e = (4u * g) / 3u;
        unsigned r = 4u * g - 3u * e;
        float x0 = x[e];
        float x1 = x[e + 1];
        float s0, s1, s2, s3, s4, s5;
        {
            float xc = fminf(fmaxf(x0, XLO), XHI);
            float f  = (xc - XLO) * inv_h;
            int i0 = min((int)f, TN - 2);
            float fr = f - (float)i0;
            unsigned e0 = t0[i0], e1 = t1[i0], e2 = t2[i0];
            float2 p0 = __half22float2(*reinterpret_cast<__half2*>(&e0));
            float2 p1 = __half22float2(*reinterpret_cast<__half2*>(&e1));
            float2 p2 = __half22float2(*reinterpret_cast<__half2*>(&e2));
            s0 = fmaf(fr, p0.y - p0.x, p0.x);
            s1 = fmaf(fr, p1.y - p1.x, p1.x);
            s2 = fmaf(fr, p2.y - p2.x, p2.x);
        }
        {
            float xc = fminf(fmaxf(x1, XLO), XHI);
            float f  = (xc - XLO) * inv_h;
            int i0 = min((int)f, TN - 2);
            float fr = f - (float)i0;
            unsigned e0 = t0[i0], e1 = t1[i0], e2 = t2[i0];
            float2 p0 = __half22float2(*reinterpret_cast<__half2*>(&e0));
            float2 p1 = __half22float2(*reinterpret_cast<__half2*>(&e1));
            float2 p2 = __half22float2(*reinterpret_cast<__half2*>(&e2));
            s3 = fmaf(fr, p0.y - p0.x, p0.x);
            s4 = fmaf(fr, p1.y - p1.x, p1.x);
            s5 = fmaf(fr, p2.y - p2.x, p2.x);
        }
        f32x4 o;
        o.x = (r == 0u) ? s0 : ((r == 1u) ? s1 : s2);
        o.y = (r == 0u) ? s1 : ((r == 1u) ? s2 : s3);
        o.z = (r == 0u) ? s2 : ((r == 1u) ? s3 : s4);
        o.w = (r == 0u) ? s3 : ((r == 1u) ? s4 : s5);
        __builtin_nontemporal_store(o, (f32x4*)(out4 + g));
    }
}

extern "C" void kernel_launch(void* const* d_in, const int* in_sizes, int n_in,
                              void* d_out, int out_size, void* d_ws, size_t ws_size,
                              hipStream_t stream) {
    const float* x  = (const float*)d_in[0];
    const float* W0 = (const float*)d_in[1];
    const float* b0 = (const float*)d_in[2];
    const float* W1 = (const float*)d_in[3];
    const float* b1 = (const float*)d_in[4];
    const float* W2 = (const float*)d_in[5];
    const float* b2 = (const float*)d_in[6];
    const float* W3 = (const float*)d_in[7];
    const float* b3 = (const float*)d_in[8];
    const float* W4 = (const float*)d_in[9];
    const float* b4 = (const float*)d_in[10];
    unsigned* tab = (unsigned*)d_ws;                          // 24 KB table
    unsigned* cnt = (unsigned*)((char*)d_ws + 3 * TN * 4);    // 4 B counter

    // reset the completion counter every call (graph-capturable memset node)
    hipMemsetAsync(cnt, 0, sizeof(unsigned), stream);

    unsigned n_out4 = (unsigned)out_size / 4u;   // 3145728
    fused_nn<<<1536, 256, 0, stream>>>(
        W0, b0, W1, b1, W2, b2, W3, b3, W4, b4,
        tab, cnt, x, (float4*)d_out, n_out4);
}

// Round 12
// 172.231 us; speedup vs baseline: 1.0065x; 1.0065x over previous
//
#include <hip/hip_runtime.h>
#include <hip/hip_fp16.h>
#include <math.h>

// f(x) = tanh-MLP(x), 1->16->32->32->16->3, per scalar element.
// R12 = R11 fused kernel with the spin changed from atomicAdd(cnt,0) RMW
// (1536-way exclusive-ownership storm -> 173us) to LOAD-ONLY relaxed
// agent-scope polling. Builders (blocks 0..511) publish the 3x2048 fp16-pair
// table + one atomicAdd each; all blocks load-poll, then stage table to LDS
// and run the streaming lerp with nontemporal stores.

#define TN 2048
#define XLO (-10.0f)
#define XHI (10.0f)
#define NBUILD 512

typedef float f32x4 __attribute__((ext_vector_type(4)));

__device__ __forceinline__ float fast_tanh(float x) {
    float t = __builtin_amdgcn_exp2f(x * 2.885390081777927f);
    return 1.0f - 2.0f * __builtin_amdgcn_rcpf(t + 1.0f);
}

__global__ __launch_bounds__(256, 6) void fused_nn(
    const float* __restrict__ W0, const float* __restrict__ b0,
    const float* __restrict__ W1, const float* __restrict__ b1,
    const float* __restrict__ W2, const float* __restrict__ b2,
    const float* __restrict__ W3, const float* __restrict__ b3,
    const float* __restrict__ W4, const float* __restrict__ b4,
    unsigned* __restrict__ tab_g, unsigned* __restrict__ cnt,
    const float* __restrict__ x, float4* __restrict__ out4, unsigned n_out4)
{
    // 24KB LDS union: phase1 weights (2212 f32) / phase2 table (3*TN u32)
    __shared__ __align__(16) unsigned smem[3 * TN];
    const int t = threadIdx.x;
    const int b = blockIdx.x;

    if (b < NBUILD) {
        float* w = (float*)smem;
        float4* w4 = (float4*)w;
        if (t < 4)   w4[t]       = ((const float4*)W0)[t];
        if (t < 4)   w4[4 + t]   = ((const float4*)b0)[t];
        if (t < 128) w4[8 + t]   = ((const float4*)W1)[t];
        if (t < 8)   w4[136 + t] = ((const float4*)b1)[t];
        w4[144 + t] = ((const float4*)W2)[t];
        if (t < 8)   w4[400 + t] = ((const float4*)b2)[t];
        if (t < 128) w4[408 + t] = ((const float4*)W3)[t];
        if (t < 4)   w4[536 + t] = ((const float4*)b3)[t];
        if (t < 12)  w4[540 + t] = ((const float4*)W4)[t];
        if (t < 3)   w[2208 + t] = b4[t];
        __syncthreads();

        const int wave = t >> 6;
        const int half = (t >> 5) & 1;
        const int sub  = t & 31;
        const int s16  = (sub < 15) ? sub : 15;
        const int e    = b * 4 + wave;
        const int p    = min(e + half, TN - 1);

        const float h = (XHI - XLO) / (float)(TN - 1);
        const float xx = XLO + (float)p * h;

        float act = fast_tanh(fmaf(xx, w[s16], w[16 + s16]));
        {
            float acc0 = w[544 + sub], acc1 = 0.f, acc2 = 0.f, acc3 = 0.f;
            #pragma unroll
            for (int k = 0; k < 16; k += 4) {
                float a0 = __shfl(act, k + 0, 32);
                float a1 = __shfl(act, k + 1, 32);
                float a2 = __shfl(act, k + 2, 32);
                float a3 = __shfl(act, k + 3, 32);
                acc0 = fmaf(a0, w[32 + (k + 0) * 32 + sub], acc0);
                acc1 = fmaf(a1, w[32 + (k + 1) * 32 + sub], acc1);
                acc2 = fmaf(a2, w[32 + (k + 2) * 32 + sub], acc2);
                acc3 = fmaf(a3, w[32 + (k + 3) * 32 + sub], acc3);
            }
            act = fast_tanh((acc0 + acc1) + (acc2 + acc3));
        }
        {
            float acc0 = w[1600 + sub], acc1 = 0.f, acc2 = 0.f, acc3 = 0.f;
            #pragma unroll
            for (int k = 0; k < 32; k += 4) {
                float a0 = __shfl(act, k + 0, 32);
                float a1 = __shfl(act, k + 1, 32);
                float a2 = __shfl(act, k + 2, 32);
                float a3 = __shfl(act, k + 3, 32);
                acc0 = fmaf(a0, w[576 + (k + 0) * 32 + sub], acc0);
                acc1 = fmaf(a1, w[576 + (k + 1) * 32 + sub], acc1);
                acc2 = fmaf(a2, w[576 + (k + 2) * 32 + sub], acc2);
                acc3 = fmaf(a3, w[576 + (k + 3) * 32 + sub], acc3);
            }
            act = fast_tanh((acc0 + acc1) + (acc2 + acc3));
        }
        {
            float acc0 = w[2144 + s16], acc1 = 0.f, acc2 = 0.f, acc3 = 0.f;
            #pragma unroll
            for (int k = 0; k < 32; k += 4) {
                float a0 = __shfl(act, k + 0, 32);
                float a1 = __shfl(act, k + 1, 32);
                float a2 = __shfl(act, k + 2, 32);
                float a3 = __shfl(act, k + 3, 32);
                acc0 = fmaf(a0, w[1632 + (k + 0) * 16 + s16], acc0);
                acc1 = fmaf(a1, w[1632 + (k + 1) * 16 + s16], acc1);
                acc2 = fmaf(a2, w[1632 + (k + 2) * 16 + s16], acc2);
                acc3 = fmaf(a3, w[1632 + (k + 3) * 16 + s16], acc3);
            }
            act = fast_tanh((acc0 + acc1) + (acc2 + acc3));
        }
        float o0 = w[2208], o1 = w[2209], o2 = w[2210];
        #pragma unroll
        for (int k = 0; k < 16; ++k) {
            float ak = __shfl(act, k, 32);
            o0 = fmaf(ak, w[2160 + k * 3 + 0], o0);
            o1 = fmaf(ak, w[2160 + k * 3 + 1], o1);
            o2 = fmaf(ak, w[2160 + k * 3 + 2], o2);
        }
        o0 = fast_tanh(o0); o1 = fast_tanh(o1); o2 = fast_tanh(o2);

        float h0 = __shfl(o0, 32, 64);
        float h1 = __shfl(o1, 32, 64);
        float h2 = __shfl(o2, 32, 64);

        if ((t & 63) == 0) {
            __half2 p0 = __floats2half2_rn(o0, h0);
            __half2 p1 = __floats2half2_rn(o1, h1);
            __half2 p2 = __floats2half2_rn(o2, h2);
            tab_g[         e] = *reinterpret_cast<unsigned*>(&p0);
            tab_g[TN     + e] = *reinterpret_cast<unsigned*>(&p1);
            tab_g[2 * TN + e] = *reinterpret_cast<unsigned*>(&p2);
        }
        __syncthreads();                 // table writes done block-wide
        __threadfence();                 // release (device scope)
        if (t == 0) atomicAdd(cnt, 1u);  // 512 RMWs total -- cheap
    }

    // ---- load-only spin (no RMW storm): 1536 leaders read the LLC line ----
    if (t == 0) {
        while (__hip_atomic_load(cnt, __ATOMIC_RELAXED,
                                 __HIP_MEMORY_SCOPE_AGENT) < NBUILD) {
            __builtin_amdgcn_s_sleep(16);
        }
    }
    __syncthreads();
    __threadfence();                     // acquire: invalidate stale lines

    // ---- phase 2: table -> LDS, streaming lerp ----
    {
        uint4* dst = (uint4*)smem;
        const uint4* src = (const uint4*)tab_g;
        for (int i = t; i < 3 * TN / 4; i += 256) dst[i] = src[i];
    }
    __syncthreads();
    const unsigned* t0 = smem;
    const unsigned* t1 = smem + TN;
    const unsigned* t2 = smem + 2 * TN;

    const float inv_h = (float)(TN - 1) / (XHI - XLO);
    unsigned stride = gridDim.x * 256u;
    for (unsigned g = b * 256u + t; g < n_out4; g += stride) {
        unsigned e = (4u * g) / 3u;
        unsigned r = 4u * g - 3u * e;
        float x0 = x[e];
        float x1 = x[e + 1];
        float s0, s1, s2, s3, s4, s5;
        {
            float xc = fminf(fmaxf(x0, XLO), XHI);
            float f  = (xc - XLO) * inv_h;
            int i0 = min((int)f, TN - 2);
            float fr = f - (float)i0;
            unsigned e0 = t0[i0], e1 = t1[i0], e2 = t2[i0];
            float2 p0 = __half22float2(*reinterpret_cast<__half2*>(&e0));
            float2 p1 = __half22float2(*reinterpret_cast<__half2*>(&e1));
            float2 p2 = __half22float2(*reinterpret_cast<__half2*>(&e2));
            s0 = fmaf(fr, p0.y - p0.x, p0.x);
            s1 = fmaf(fr, p1.y - p1.x, p1.x);
            s2 = fmaf(fr, p2.y - p2.x, p2.x);
        }
        {
            float xc = fminf(fmaxf(x1, XLO), XHI);
            float f  = (xc - XLO) * inv_h;
            int i0 = min((int)f, TN - 2);
            float fr = f - (float)i0;
            unsigned e0 = t0[i0], e1 = t1[i0], e2 = t2[i0];
            float2 p0 = __half22float2(*reinterpret_cast<__half2*>(&e0));
            float2 p1 = __half22float2(*reinterpret_cast<__half2*>(&e1));
            float2 p2 = __half22float2(*reinterpret_cast<__half2*>(&e2));
            s3 = fmaf(fr, p0.y - p0.x, p0.x);
            s4 = fmaf(fr, p1.y - p1.x, p1.x);
            s5 = fmaf(fr, p2.y - p2.x, p2.x);
        }
        f32x4 o;
        o.x = (r == 0u) ? s0 : ((r == 1u) ? s1 : s2);
        o.y = (r == 0u) ? s1 : ((r == 1u) ? s2 : s3);
        o.z = (r == 0u) ? s2 : ((r == 1u) ? s3 : s4);
        o.w = (r == 0u) ? s3 : ((r == 1u) ? s4 : s5);
        __builtin_nontemporal_store(o, (f32x4*)(out4 + g));
    }
}

extern "C" void kernel_launch(void* const* d_in, const int* in_sizes, int n_in,
                              void* d_out, int out_size, void* d_ws, size_t ws_size,
                              hipStream_t stream) {
    const float* x  = (const float*)d_in[0];
    const float* W0 = (const float*)d_in[1];
    const float* b0 = (const float*)d_in[2];
    const float* W1 = (const float*)d_in[3];
    const float* b1 = (const float*)d_in[4];
    const float* W2 = (const float*)d_in[5];
    const float* b2 = (const float*)d_in[6];
    const float* W3 = (const float*)d_in[7];
    const float* b3 = (const float*)d_in[8];
    const float* W4 = (const float*)d_in[9];
    const float* b4 = (const float*)d_in[10];
    unsigned* tab = (unsigned*)d_ws;                          // 24 KB table
    unsigned* cnt = (unsigned*)((char*)d_ws + 3 * TN * 4);    // 4 B counter

    hipMemsetAsync(cnt, 0, sizeof(unsigned), stream);         // reset flag

    unsigned n_out4 = (unsigned)out_size / 4u;   // 3145728
    fused_nn<<<1536, 256, 0, stream>>>(
        W0, b0, W1, b1, W2, b2, W3, b3, W4, b4,
        tab, cnt, x, (float4*)d_out, n_out4);
}

// Round 13
// 147.533 us; speedup vs baseline: 1.1750x; 1.1674x over previous
//
#include <hip/hip_runtime.h>
#include <hip/hip_fp16.h>
#include <math.h>

// f(x) = tanh-MLP(x), 1->16->32->32->16->3, per scalar element.
// R13: fused kernel, two-level sync.
//   builders (blocks 0..511): build 3x2048 fp16-pair table -> atomicAdd(cnt).
//   block 0 leader: polls cnt (sc0sc1 loads), then ONE release-store to done.
//   all other leaders: poll done (read-only line, written once) with
//   sc0sc1 loads + s_sleep(32). No RMW/poll interference, no staleness.
//   While waiting, every block streams its x-slice into the LLC (asm-sinked)
//   so the apply phase's reads are cache-hits (apply ~= write-bound).

#define TN 2048
#define XLO (-10.0f)
#define XHI (10.0f)
#define NBUILD 512

typedef float f32x4 __attribute__((ext_vector_type(4)));

__device__ __forceinline__ float fast_tanh(float x) {
    float t = __builtin_amdgcn_exp2f(x * 2.885390081777927f);
    return 1.0f - 2.0f * __builtin_amdgcn_rcpf(t + 1.0f);
}

// coherent dword load: bypasses L1/L2 (sc0 sc1), fresh from LLC
__device__ __forceinline__ unsigned load_sc01(const unsigned* p) {
    unsigned v;
    asm volatile("global_load_dword %0, %1, off sc0 sc1\n\t"
                 "s_waitcnt vmcnt(0)"
                 : "=v"(v) : "v"(p) : "memory");
    return v;
}

__global__ __launch_bounds__(256, 6) void fused_nn(
    const float* __restrict__ W0, const float* __restrict__ b0,
    const float* __restrict__ W1, const float* __restrict__ b1,
    const float* __restrict__ W2, const float* __restrict__ b2,
    const float* __restrict__ W3, const float* __restrict__ b3,
    const float* __restrict__ W4, const float* __restrict__ b4,
    unsigned* __restrict__ tab_g, unsigned* __restrict__ cnt,
    unsigned* __restrict__ done,
    const float* __restrict__ x, float4* __restrict__ out4, unsigned n_out4)
{
    __shared__ __align__(16) unsigned smem[3 * TN];   // 24 KB
    const int t = threadIdx.x;
    const int b = blockIdx.x;

    // ---- phase 1: builders compute the table ----
    if (b < NBUILD) {
        float* w = (float*)smem;
        float4* w4 = (float4*)w;
        if (t < 4)   w4[t]       = ((const float4*)W0)[t];
        if (t < 4)   w4[4 + t]   = ((const float4*)b0)[t];
        if (t < 128) w4[8 + t]   = ((const float4*)W1)[t];
        if (t < 8)   w4[136 + t] = ((const float4*)b1)[t];
        w4[144 + t] = ((const float4*)W2)[t];
        if (t < 8)   w4[400 + t] = ((const float4*)b2)[t];
        if (t < 128) w4[408 + t] = ((const float4*)W3)[t];
        if (t < 4)   w4[536 + t] = ((const float4*)b3)[t];
        if (t < 12)  w4[540 + t] = ((const float4*)W4)[t];
        if (t < 3)   w[2208 + t] = b4[t];
        __syncthreads();

        const int wave = t >> 6;
        const int half = (t >> 5) & 1;
        const int sub  = t & 31;
        const int s16  = (sub < 15) ? sub : 15;
        const int e    = b * 4 + wave;
        const int p    = min(e + half, TN - 1);

        const float h = (XHI - XLO) / (float)(TN - 1);
        const float xx = XLO + (float)p * h;

        float act = fast_tanh(fmaf(xx, w[s16], w[16 + s16]));
        {
            float acc0 = w[544 + sub], acc1 = 0.f, acc2 = 0.f, acc3 = 0.f;
            #pragma unroll
            for (int k = 0; k < 16; k += 4) {
                float a0 = __shfl(act, k + 0, 32);
                float a1 = __shfl(act, k + 1, 32);
                float a2 = __shfl(act, k + 2, 32);
                float a3 = __shfl(act, k + 3, 32);
                acc0 = fmaf(a0, w[32 + (k + 0) * 32 + sub], acc0);
                acc1 = fmaf(a1, w[32 + (k + 1) * 32 + sub], acc1);
                acc2 = fmaf(a2, w[32 + (k + 2) * 32 + sub], acc2);
                acc3 = fmaf(a3, w[32 + (k + 3) * 32 + sub], acc3);
            }
            act = fast_tanh((acc0 + acc1) + (acc2 + acc3));
        }
        {
            float acc0 = w[1600 + sub], acc1 = 0.f, acc2 = 0.f, acc3 = 0.f;
            #pragma unroll
            for (int k = 0; k < 32; k += 4) {
                float a0 = __shfl(act, k + 0, 32);
                float a1 = __shfl(act, k + 1, 32);
                float a2 = __shfl(act, k + 2, 32);
                float a3 = __shfl(act, k + 3, 32);
                acc0 = fmaf(a0, w[576 + (k + 0) * 32 + sub], acc0);
                acc1 = fmaf(a1, w[576 + (k + 1) * 32 + sub], acc1);
                acc2 = fmaf(a2, w[576 + (k + 2) * 32 + sub], acc2);
                acc3 = fmaf(a3, w[576 + (k + 3) * 32 + sub], acc3);
            }
            act = fast_tanh((acc0 + acc1) + (acc2 + acc3));
        }
        {
            float acc0 = w[2144 + s16], acc1 = 0.f, acc2 = 0.f, acc3 = 0.f;
            #pragma unroll
            for (int k = 0; k < 32; k += 4) {
                float a0 = __shfl(act, k + 0, 32);
                float a1 = __shfl(act, k + 1, 32);
                float a2 = __shfl(act, k + 2, 32);
                float a3 = __shfl(act, k + 3, 32);
                acc0 = fmaf(a0, w[1632 + (k + 0) * 16 + s16], acc0);
                acc1 = fmaf(a1, w[1632 + (k + 1) * 16 + s16], acc1);
                acc2 = fmaf(a2, w[1632 + (k + 2) * 16 + s16], acc2);
                acc3 = fmaf(a3, w[1632 + (k + 3) * 16 + s16], acc3);
            }
            act = fast_tanh((acc0 + acc1) + (acc2 + acc3));
        }
        float o0 = w[2208], o1 = w[2209], o2 = w[2210];
        #pragma unroll
        for (int k = 0; k < 16; ++k) {
            float ak = __shfl(act, k, 32);
            o0 = fmaf(ak, w[2160 + k * 3 + 0], o0);
            o1 = fmaf(ak, w[2160 + k * 3 + 1], o1);
            o2 = fmaf(ak, w[2160 + k * 3 + 2], o2);
        }
        o0 = fast_tanh(o0); o1 = fast_tanh(o1); o2 = fast_tanh(o2);

        float h0 = __shfl(o0, 32, 64);
        float h1 = __shfl(o1, 32, 64);
        float h2 = __shfl(o2, 32, 64);

        if ((t & 63) == 0) {
            __half2 p0 = __floats2half2_rn(o0, h0);
            __half2 p1 = __floats2half2_rn(o1, h1);
            __half2 p2 = __floats2half2_rn(o2, h2);
            tab_g[         e] = *reinterpret_cast<unsigned*>(&p0);
            tab_g[TN     + e] = *reinterpret_cast<unsigned*>(&p1);
            tab_g[2 * TN + e] = *reinterpret_cast<unsigned*>(&p2);
        }
        __syncthreads();
        __threadfence();                  // release table writes to LLC
        if (t == 0) atomicAdd(cnt, 1u);   // 512 RMWs total; nobody polls this
    }

    // ---- warm the LLC with x while the build finishes (asm-sinked) ----
    {
        const float4* x4 = (const float4*)x;
        unsigned nx4 = n_out4 / 3u;       // 1048576 float4 x-chunks
        f32x4 s = {0.f, 0.f, 0.f, 0.f};
        for (unsigned i = b * 256u + t; i < nx4; i += 1536u * 256u) {
            f32x4 v = *(const f32x4*)(x4 + i);
            s += v;
        }
        asm volatile("" :: "v"(s.x), "v"(s.y), "v"(s.z), "v"(s.w));
    }

    // ---- two-level sync ----
    if (t == 0) {
        if (b == 0) {
            while (load_sc01(cnt) < NBUILD) __builtin_amdgcn_s_sleep(8);
            __hip_atomic_store(done, 1u, __ATOMIC_RELEASE,
                               __HIP_MEMORY_SCOPE_AGENT);
        } else {
            while (load_sc01(done) == 0u) __builtin_amdgcn_s_sleep(32);
        }
    }
    __syncthreads();
    __threadfence();                      // acquire: drop stale L2 lines

    // ---- phase 2: table -> LDS, streaming lerp ----
    {
        uint4* dst = (uint4*)smem;
        const uint4* src = (const uint4*)tab_g;
        for (int i = t; i < 3 * TN / 4; i += 256) dst[i] = src[i];
    }
    __syncthreads();
    const unsigned* t0 = smem;
    const unsigned* t1 = smem + TN;
    const unsigned* t2 = smem + 2 * TN;

    const float inv_h = (float)(TN - 1) / (XHI - XLO);
    unsigned stride = gridDim.x * 256u;
    for (unsigned g = b * 256u + t; g < n_out4; g += stride) {
        unsigned e = (4u * g) / 3u;
        unsigned r = 4u * g - 3u * e;
        float x0 = x[e];
        float x1 = x[e + 1];
        float s0, s1, s2, s3, s4, s5;
        {
            float xc = fminf(fmaxf(x0, XLO), XHI);
            float f  = (xc - XLO) * inv_h;
            int i0 = min((int)f, TN - 2);
            float fr = f - (float)i0;
            unsigned e0 = t0[i0], e1 = t1[i0], e2 = t2[i0];
            float2 p0 = __half22float2(*reinterpret_cast<__half2*>(&e0));
            float2 p1 = __half22float2(*reinterpret_cast<__half2*>(&e1));
            float2 p2 = __half22float2(*reinterpret_cast<__half2*>(&e2));
            s0 = fmaf(fr, p0.y - p0.x, p0.x);
            s1 = fmaf(fr, p1.y - p1.x, p1.x);
            s2 = fmaf(fr, p2.y - p2.x, p2.x);
        }
        {
            float xc = fminf(fmaxf(x1, XLO), XHI);
            float f  = (xc - XLO) * inv_h;
            int i0 = min((int)f, TN - 2);
            float fr = f - (float)i0;
            unsigned e0 = t0[i0], e1 = t1[i0], e2 = t2[i0];
            float2 p0 = __half22float2(*reinterpret_cast<__half2*>(&e0));
            float2 p1 = __half22float2(*reinterpret_cast<__half2*>(&e1));
            float2 p2 = __half22float2(*reinterpret_cast<__half2*>(&e2));
            s3 = fmaf(fr, p0.y - p0.x, p0.x);
            s4 = fmaf(fr, p1.y - p1.x, p1.x);
            s5 = fmaf(fr, p2.y - p2.x, p2.x);
        }
        f32x4 o;
        o.x = (r == 0u) ? s0 : ((r == 1u) ? s1 : s2);
        o.y = (r == 0u) ? s1 : ((r == 1u) ? s2 : s3);
        o.z = (r == 0u) ? s2 : ((r == 1u) ? s3 : s4);
        o.w = (r == 0u) ? s3 : ((r == 1u) ? s4 : s5);
        __builtin_nontemporal_store(o, (f32x4*)(out4 + g));
    }
}

extern "C" void kernel_launch(void* const* d_in, const int* in_sizes, int n_in,
                              void* d_out, int out_size, void* d_ws, size_t ws_size,
                              hipStream_t stream) {
    const float* x  = (const float*)d_in[0];
    const float* W0 = (const float*)d_in[1];
    const float* b0 = (const float*)d_in[2];
    const float* W1 = (const float*)d_in[3];
    const float* b1 = (const float*)d_in[4];
    const float* W2 = (const float*)d_in[5];
    const float* b2 = (const float*)d_in[6];
    const float* W3 = (const float*)d_in[7];
    const float* b3 = (const float*)d_in[8];
    const float* W4 = (const float*)d_in[9];
    const float* b4 = (const float*)d_in[10];
    unsigned* tab  = (unsigned*)d_ws;                          // 24 KB table
    unsigned* cnt  = (unsigned*)((char*)d_ws + 3 * TN * 4);    // own line
    unsigned* done = (unsigned*)((char*)d_ws + 3 * TN * 4 + 128); // own line

    // reset both flags (one 256B memset node, graph-capturable)
    hipMemsetAsync((char*)d_ws + 3 * TN * 4, 0, 256, stream);

    unsigned n_out4 = (unsigned)out_size / 4u;   // 3145728
    fused_nn<<<1536, 256, 0, stream>>>(
        W0, b0, W1, b1, W2, b2, W3, b3, W4, b4,
        tab, cnt, done, x, (float4*)d_out, n_out4);
}

// Round 14
// 33.538 us; speedup vs baseline: 5.1687x; 4.3990x over previous
//
#include <hip/hip_runtime.h>
#include <hip/hip_fp16.h>
#include <math.h>

// f(x) = tanh-MLP(x), 1->16->32->32->16->3, per scalar element.
// R14: fused kernel, ZERO threadfences (R11-R13's 143-173us was 512 builder
// blocks each issuing a device-scope release fence = L2-writeback storm).
//   builders (blocks 0..511): table entries via WRITE-THROUGH sc0sc1 stores
//     (data lands at LLC; no dirty L2, no fence), vmcnt(0), atomicAdd(cnt).
//   block 0: polls cnt (sc0sc1), then one sc0sc1 store to done.
//   others: poll done (sc0sc1 + s_sleep). Consumers stage the table with
//     sc0sc1 LOADS (LLC-fresh; no acquire fence). Apply = R10 streaming lerp.

#define TN 2048
#define XLO (-10.0f)
#define XHI (10.0f)
#define NBUILD 512

typedef float f32x4 __attribute__((ext_vector_type(4)));

__device__ __forceinline__ float fast_tanh(float x) {
    float t = __builtin_amdgcn_exp2f(x * 2.885390081777927f);
    return 1.0f - 2.0f * __builtin_amdgcn_rcpf(t + 1.0f);
}

__device__ __forceinline__ unsigned load_sc01(const unsigned* p) {
    unsigned v;
    asm volatile("global_load_dword %0, %1, off sc0 sc1\n\t"
                 "s_waitcnt vmcnt(0)"
                 : "=v"(v) : "v"(p) : "memory");
    return v;
}

__device__ __forceinline__ void store_sc01(unsigned* p, unsigned v) {
    asm volatile("global_store_dword %0, %1, off sc0 sc1"
                 :: "v"(p), "v"(v) : "memory");
}

__device__ __forceinline__ uint4 load4_sc01(const uint4* p) {
    uint4 v;
    asm volatile("global_load_dwordx4 %0, %1, off sc0 sc1\n\t"
                 "s_waitcnt vmcnt(0)"
                 : "=v"(v) : "v"(p) : "memory");
    return v;
}

__global__ __launch_bounds__(256, 6) void fused_nn(
    const float* __restrict__ W0, const float* __restrict__ b0,
    const float* __restrict__ W1, const float* __restrict__ b1,
    const float* __restrict__ W2, const float* __restrict__ b2,
    const float* __restrict__ W3, const float* __restrict__ b3,
    const float* __restrict__ W4, const float* __restrict__ b4,
    unsigned* __restrict__ tab_g, unsigned* __restrict__ cnt,
    unsigned* __restrict__ done,
    const float* __restrict__ x, float4* __restrict__ out4, unsigned n_out4)
{
    __shared__ __align__(16) unsigned smem[3 * TN];   // 24 KB
    const int t = threadIdx.x;
    const int b = blockIdx.x;

    // ---- phase 1: builders compute the table ----
    if (b < NBUILD) {
        float* w = (float*)smem;
        float4* w4 = (float4*)w;
        if (t < 4)   w4[t]       = ((const float4*)W0)[t];
        if (t < 4)   w4[4 + t]   = ((const float4*)b0)[t];
        if (t < 128) w4[8 + t]   = ((const float4*)W1)[t];
        if (t < 8)   w4[136 + t] = ((const float4*)b1)[t];
        w4[144 + t] = ((const float4*)W2)[t];
        if (t < 8)   w4[400 + t] = ((const float4*)b2)[t];
        if (t < 128) w4[408 + t] = ((const float4*)W3)[t];
        if (t < 4)   w4[536 + t] = ((const float4*)b3)[t];
        if (t < 12)  w4[540 + t] = ((const float4*)W4)[t];
        if (t < 3)   w[2208 + t] = b4[t];
        __syncthreads();

        const int wave = t >> 6;
        const int half = (t >> 5) & 1;
        const int sub  = t & 31;
        const int s16  = (sub < 15) ? sub : 15;
        const int e    = b * 4 + wave;
        const int p    = min(e + half, TN - 1);

        const float h = (XHI - XLO) / (float)(TN - 1);
        const float xx = XLO + (float)p * h;

        float act = fast_tanh(fmaf(xx, w[s16], w[16 + s16]));
        {
            float acc0 = w[544 + sub], acc1 = 0.f, acc2 = 0.f, acc3 = 0.f;
            #pragma unroll
            for (int k = 0; k < 16; k += 4) {
                float a0 = __shfl(act, k + 0, 32);
                float a1 = __shfl(act, k + 1, 32);
                float a2 = __shfl(act, k + 2, 32);
                float a3 = __shfl(act, k + 3, 32);
                acc0 = fmaf(a0, w[32 + (k + 0) * 32 + sub], acc0);
                acc1 = fmaf(a1, w[32 + (k + 1) * 32 + sub], acc1);
                acc2 = fmaf(a2, w[32 + (k + 2) * 32 + sub], acc2);
                acc3 = fmaf(a3, w[32 + (k + 3) * 32 + sub], acc3);
            }
            act = fast_tanh((acc0 + acc1) + (acc2 + acc3));
        }
        {
            float acc0 = w[1600 + sub], acc1 = 0.f, acc2 = 0.f, acc3 = 0.f;
            #pragma unroll
            for (int k = 0; k < 32; k += 4) {
                float a0 = __shfl(act, k + 0, 32);
                float a1 = __shfl(act, k + 1, 32);
                float a2 = __shfl(act, k + 2, 32);
                float a3 = __shfl(act, k + 3, 32);
                acc0 = fmaf(a0, w[576 + (k + 0) * 32 + sub], acc0);
                acc1 = fmaf(a1, w[576 + (k + 1) * 32 + sub], acc1);
                acc2 = fmaf(a2, w[576 + (k + 2) * 32 + sub], acc2);
                acc3 = fmaf(a3, w[576 + (k + 3) * 32 + sub], acc3);
            }
            act = fast_tanh((acc0 + acc1) + (acc2 + acc3));
        }
        {
            float acc0 = w[2144 + s16], acc1 = 0.f, acc2 = 0.f, acc3 = 0.f;
            #pragma unroll
            for (int k = 0; k < 32; k += 4) {
                float a0 = __shfl(act, k + 0, 32);
                float a1 = __shfl(act, k + 1, 32);
                float a2 = __shfl(act, k + 2, 32);
                float a3 = __shfl(act, k + 3, 32);
                acc0 = fmaf(a0, w[1632 + (k + 0) * 16 + s16], acc0);
                acc1 = fmaf(a1, w[1632 + (k + 1) * 16 + s16], acc1);
                acc2 = fmaf(a2, w[1632 + (k + 2) * 16 + s16], acc2);
                acc3 = fmaf(a3, w[1632 + (k + 3) * 16 + s16], acc3);
            }
            act = fast_tanh((acc0 + acc1) + (acc2 + acc3));
        }
        float o0 = w[2208], o1 = w[2209], o2 = w[2210];
        #pragma unroll
        for (int k = 0; k < 16; ++k) {
            float ak = __shfl(act, k, 32);
            o0 = fmaf(ak, w[2160 + k * 3 + 0], o0);
            o1 = fmaf(ak, w[2160 + k * 3 + 1], o1);
            o2 = fmaf(ak, w[2160 + k * 3 + 2], o2);
        }
        o0 = fast_tanh(o0); o1 = fast_tanh(o1); o2 = fast_tanh(o2);

        float h0 = __shfl(o0, 32, 64);
        float h1 = __shfl(o1, 32, 64);
        float h2 = __shfl(o2, 32, 64);

        if ((t & 63) == 0) {
            __half2 p0 = __floats2half2_rn(o0, h0);
            __half2 p1 = __floats2half2_rn(o1, h1);
            __half2 p2 = __floats2half2_rn(o2, h2);
            // write-through to LLC: no dirty L2 line, no fence needed
            store_sc01(&tab_g[         e], *reinterpret_cast<unsigned*>(&p0));
            store_sc01(&tab_g[TN     + e], *reinterpret_cast<unsigned*>(&p1));
            store_sc01(&tab_g[2 * TN + e], *reinterpret_cast<unsigned*>(&p2));
            asm volatile("s_waitcnt vmcnt(0)" ::: "memory");
        }
        __syncthreads();                 // all 4 waves' stores retired
        if (t == 0) atomicAdd(cnt, 1u);  // coherence-point RMW = the release
    }

    // ---- two-level sync, no fences ----
    if (t == 0) {
        if (b == 0) {
            while (load_sc01(cnt) < NBUILD) __builtin_amdgcn_s_sleep(2);
            store_sc01(done, 1u);
            asm volatile("s_waitcnt vmcnt(0)" ::: "memory");
        } else {
            while (load_sc01(done) == 0u) __builtin_amdgcn_s_sleep(32);
        }
    }
    __syncthreads();

    // ---- phase 2: table -> LDS via LLC-coherent loads, then lerp ----
    {
        uint4* dst = (uint4*)smem;
        const uint4* src = (const uint4*)tab_g;
        for (int i = t; i < 3 * TN / 4; i += 256) dst[i] = load4_sc01(src + i);
    }
    __syncthreads();
    const unsigned* t0 = smem;
    const unsigned* t1 = smem + TN;
    const unsigned* t2 = smem + 2 * TN;

    const float inv_h = (float)(TN - 1) / (XHI - XLO);
    unsigned stride = gridDim.x * 256u;
    for (unsigned g = b * 256u + t; g < n_out4; g += stride) {
        unsigned e = (4u * g) / 3u;
        unsigned r = 4u * g - 3u * e;
        float x0 = x[e];
        float x1 = x[e + 1];
        float s0, s1, s2, s3, s4, s5;
        {
            float xc = fminf(fmaxf(x0, XLO), XHI);
            float f  = (xc - XLO) * inv_h;
            int i0 = min((int)f, TN - 2);
            float fr = f - (float)i0;
            unsigned e0 = t0[i0], e1 = t1[i0], e2 = t2[i0];
            float2 p0 = __half22float2(*reinterpret_cast<__half2*>(&e0));
            float2 p1 = __half22float2(*reinterpret_cast<__half2*>(&e1));
            float2 p2 = __half22float2(*reinterpret_cast<__half2*>(&e2));
            s0 = fmaf(fr, p0.y - p0.x, p0.x);
            s1 = fmaf(fr, p1.y - p1.x, p1.x);
            s2 = fmaf(fr, p2.y - p2.x, p2.x);
        }
        {
            float xc = fminf(fmaxf(x1, XLO), XHI);
            float f  = (xc - XLO) * inv_h;
            int i0 = min((int)f, TN - 2);
            float fr = f - (float)i0;
            unsigned e0 = t0[i0], e1 = t1[i0], e2 = t2[i0];
            float2 p0 = __half22float2(*reinterpret_cast<__half2*>(&e0));
            float2 p1 = __half22float2(*reinterpret_cast<__half2*>(&e1));
            float2 p2 = __half22float2(*reinterpret_cast<__half2*>(&e2));
            s3 = fmaf(fr, p0.y - p0.x, p0.x);
            s4 = fmaf(fr, p1.y - p1.x, p1.x);
            s5 = fmaf(fr, p2.y - p2.x, p2.x);
        }
        f32x4 o;
        o.x = (r == 0u) ? s0 : ((r == 1u) ? s1 : s2);
        o.y = (r == 0u) ? s1 : ((r == 1u) ? s2 : s3);
        o.z = (r == 0u) ? s2 : ((r == 1u) ? s3 : s4);
        o.w = (r == 0u) ? s3 : ((r == 1u) ? s4 : s5);
        __builtin_nontemporal_store(o, (f32x4*)(out4 + g));
    }
}

extern "C" void kernel_launch(void* const* d_in, const int* in_sizes, int n_in,
                              void* d_out, int out_size, void* d_ws, size_t ws_size,
                              hipStream_t stream) {
    const float* x  = (const float*)d_in[0];
    const float* W0 = (const float*)d_in[1];
    const float* b0 = (const float*)d_in[2];
    const float* W1 = (const float*)d_in[3];
    const float* b1 = (const float*)d_in[4];
    const float* W2 = (const float*)d_in[5];
    const float* b2 = (const float*)d_in[6];
    const float* W3 = (const float*)d_in[7];
    const float* b3 = (const float*)d_in[8];
    const float* W4 = (const float*)d_in[9];
    const float* b4 = (const float*)d_in[10];
    unsigned* tab  = (unsigned*)d_ws;                             // 24 KB
    unsigned* cnt  = (unsigned*)((char*)d_ws + 3 * TN * 4);       // own line
    unsigned* done = (unsigned*)((char*)d_ws + 3 * TN * 4 + 128); // own line

    hipMemsetAsync((char*)d_ws + 3 * TN * 4, 0, 256, stream);     // reset flags

    unsigned n_out4 = (unsigned)out_size / 4u;   // 3145728
    fused_nn<<<1536, 256, 0, stream>>>(
        W0, b0, W1, b1, W2, b2, W3, b3, W4, b4,
        tab, cnt, done, x, (float4*)d_out, n_out4);
}

// Round 15
// 29.536 us; speedup vs baseline: 5.8689x; 1.1355x over previous
//
#include <hip/hip_runtime.h>
#include <hip/hip_fp16.h>
#include <math.h>

// f(x) = tanh-MLP(x), 1->16->32->32->16->3, per scalar element.
// R15 = R10 (best: 23.9us) with build_table launched TWICE (identical
// deterministic output). Probe: dur - 23.9 = true build cost, splitting
// the 11.4us "build + fixed overhead" residual. R14's fused-kernel path
// is abandoned (spin sync floor 33.5us > two-kernel 23.9us).

#define TN 2048
#define XLO (-10.0f)
#define XHI (10.0f)

typedef float f32x4 __attribute__((ext_vector_type(4)));

__device__ __forceinline__ float fast_tanh(float x) {
    float t = __builtin_amdgcn_exp2f(x * 2.885390081777927f);
    return 1.0f - 2.0f * __builtin_amdgcn_rcpf(t + 1.0f);
}

// LDS float layout (raw row-major):
//   W0@0[16] b0@16[16] W1@32[16][32] b1@544[32] W2@576[32][32] b2@1600[32]
//   W3@1632[32][16] b3@2144[16] W4@2160[16][3] b4@2208[3]
__global__ __launch_bounds__(256) void build_table(
    const float* __restrict__ W0, const float* __restrict__ b0,
    const float* __restrict__ W1, const float* __restrict__ b1,
    const float* __restrict__ W2, const float* __restrict__ b2,
    const float* __restrict__ W3, const float* __restrict__ b3,
    const float* __restrict__ W4, const float* __restrict__ b4,
    unsigned* __restrict__ tab_g)
{
    __shared__ __align__(16) float w[2212];
    const int t = threadIdx.x;
    float4* w4 = (float4*)w;

    if (t < 4)   w4[t]       = ((const float4*)W0)[t];
    if (t < 4)   w4[4 + t]   = ((const float4*)b0)[t];
    if (t < 128) w4[8 + t]   = ((const float4*)W1)[t];
    if (t < 8)   w4[136 + t] = ((const float4*)b1)[t];
    w4[144 + t] = ((const float4*)W2)[t];               // 256 float4s
    if (t < 8)   w4[400 + t] = ((const float4*)b2)[t];
    if (t < 128) w4[408 + t] = ((const float4*)W3)[t];
    if (t < 4)   w4[536 + t] = ((const float4*)b3)[t];
    if (t < 12)  w4[540 + t] = ((const float4*)W4)[t];
    if (t < 3)   w[2208 + t] = b4[t];
    __syncthreads();

    const int wave = t >> 6;
    const int half = (t >> 5) & 1;
    const int sub  = t & 31;
    const int s16  = (sub < 15) ? sub : 15;
    const int e    = blockIdx.x * 4 + wave;
    const int p    = min(e + half, TN - 1);

    const float h = (XHI - XLO) / (float)(TN - 1);
    const float x = XLO + (float)p * h;

    float act = fast_tanh(fmaf(x, w[s16], w[16 + s16]));
    {
        float acc0 = w[544 + sub], acc1 = 0.f, acc2 = 0.f, acc3 = 0.f;
        #pragma unroll
        for (int k = 0; k < 16; k += 4) {
            float a0 = __shfl(act, k + 0, 32);
            float a1 = __shfl(act, k + 1, 32);
            float a2 = __shfl(act, k + 2, 32);
            float a3 = __shfl(act, k + 3, 32);
            acc0 = fmaf(a0, w[32 + (k + 0) * 32 + sub], acc0);
            acc1 = fmaf(a1, w[32 + (k + 1) * 32 + sub], acc1);
            acc2 = fmaf(a2, w[32 + (k + 2) * 32 + sub], acc2);
            acc3 = fmaf(a3, w[32 + (k + 3) * 32 + sub], acc3);
        }
        act = fast_tanh((acc0 + acc1) + (acc2 + acc3));
    }
    {
        float acc0 = w[1600 + sub], acc1 = 0.f, acc2 = 0.f, acc3 = 0.f;
        #pragma unroll
        for (int k = 0; k < 32; k += 4) {
            float a0 = __shfl(act, k + 0, 32);
            float a1 = __shfl(act, k + 1, 32);
            float a2 = __shfl(act, k + 2, 32);
            float a3 = __shfl(act, k + 3, 32);
            acc0 = fmaf(a0, w[576 + (k + 0) * 32 + sub], acc0);
            acc1 = fmaf(a1, w[576 + (k + 1) * 32 + sub], acc1);
            acc2 = fmaf(a2, w[576 + (k + 2) * 32 + sub], acc2);
            acc3 = fmaf(a3, w[576 + (k + 3) * 32 + sub], acc3);
        }
        act = fast_tanh((acc0 + acc1) + (acc2 + acc3));
    }
    {
        float acc0 = w[2144 + s16], acc1 = 0.f, acc2 = 0.f, acc3 = 0.f;
        #pragma unroll
        for (int k = 0; k < 32; k += 4) {
            float a0 = __shfl(act, k + 0, 32);
            float a1 = __shfl(act, k + 1, 32);
            float a2 = __shfl(act, k + 2, 32);
            float a3 = __shfl(act, k + 3, 32);
            acc0 = fmaf(a0, w[1632 + (k + 0) * 16 + s16], acc0);
            acc1 = fmaf(a1, w[1632 + (k + 1) * 16 + s16], acc1);
            acc2 = fmaf(a2, w[1632 + (k + 2) * 16 + s16], acc2);
            acc3 = fmaf(a3, w[1632 + (k + 3) * 16 + s16], acc3);
        }
        act = fast_tanh((acc0 + acc1) + (acc2 + acc3));
    }
    float o0 = w[2208], o1 = w[2209], o2 = w[2210];
    #pragma unroll
    for (int k = 0; k < 16; ++k) {
        float ak = __shfl(act, k, 32);
        o0 = fmaf(ak, w[2160 + k * 3 + 0], o0);
        o1 = fmaf(ak, w[2160 + k * 3 + 1], o1);
        o2 = fmaf(ak, w[2160 + k * 3 + 2], o2);
    }
    o0 = fast_tanh(o0); o1 = fast_tanh(o1); o2 = fast_tanh(o2);

    float h0 = __shfl(o0, 32, 64);
    float h1 = __shfl(o1, 32, 64);
    float h2 = __shfl(o2, 32, 64);

    if ((t & 63) == 0) {
        __half2 p0 = __floats2half2_rn(o0, h0);   // .x=f(e), .y=f(e+1)
        __half2 p1 = __floats2half2_rn(o1, h1);
        __half2 p2 = __floats2half2_rn(o2, h2);
        tab_g[         e] = *reinterpret_cast<unsigned*>(&p0);
        tab_g[TN     + e] = *reinterpret_cast<unsigned*>(&p1);
        tab_g[2 * TN + e] = *reinterpret_cast<unsigned*>(&p2);
    }
}

__device__ __forceinline__ void lerp3s(
    const unsigned* __restrict__ t0, const unsigned* __restrict__ t1,
    const unsigned* __restrict__ t2, float inv_h, float x,
    float& y0, float& y1, float& y2)
{
    float xc = fminf(fmaxf(x, XLO), XHI);
    float f  = (xc - XLO) * inv_h;
    int i0 = (int)f;
    i0 = min(i0, TN - 2);
    float fr = f - (float)i0;
    unsigned e0 = t0[i0];
    unsigned e1 = t1[i0];
    unsigned e2 = t2[i0];
    float2 p0 = __half22float2(*reinterpret_cast<__half2*>(&e0));
    float2 p1 = __half22float2(*reinterpret_cast<__half2*>(&e1));
    float2 p2 = __half22float2(*reinterpret_cast<__half2*>(&e2));
    y0 = fmaf(fr, p0.y - p0.x, p0.x);
    y1 = fmaf(fr, p1.y - p1.x, p1.x);
    y2 = fmaf(fr, p2.y - p2.x, p2.x);
}

__global__ __launch_bounds__(256) void apply_s(
    const float* __restrict__ x, const unsigned* __restrict__ tab_g,
    float4* __restrict__ out4, unsigned n_out4)
{
    __shared__ __align__(16) unsigned tab[3 * TN];
    {
        uint4* dst = (uint4*)tab;
        const uint4* src = (const uint4*)tab_g;
        for (int i = threadIdx.x; i < 3 * TN / 4; i += 256) dst[i] = src[i];
    }
    __syncthreads();
    const unsigned* t0 = tab;
    const unsigned* t1 = tab + TN;
    const unsigned* t2 = tab + 2 * TN;

    const float inv_h = (float)(TN - 1) / (XHI - XLO);
    unsigned stride = gridDim.x * 256u;
    for (unsigned g = blockIdx.x * 256u + threadIdx.x; g < n_out4; g += stride) {
        unsigned e = (4u * g) / 3u;
        unsigned r = 4u * g - 3u * e;
        float x0 = x[e];
        float x1 = x[e + 1];
        float s0, s1, s2, s3, s4, s5;
        lerp3s(t0, t1, t2, inv_h, x0, s0, s1, s2);
        lerp3s(t0, t1, t2, inv_h, x1, s3, s4, s5);
        f32x4 o;
        o.x = (r == 0u) ? s0 : ((r == 1u) ? s1 : s2);
        o.y = (r == 0u) ? s1 : ((r == 1u) ? s2 : s3);
        o.z = (r == 0u) ? s2 : ((r == 1u) ? s3 : s4);
        o.w = (r == 0u) ? s3 : ((r == 1u) ? s4 : s5);
        __builtin_nontemporal_store(o, (f32x4*)(out4 + g));
    }
}

extern "C" void kernel_launch(void* const* d_in, const int* in_sizes, int n_in,
                              void* d_out, int out_size, void* d_ws, size_t ws_size,
                              hipStream_t stream) {
    const float* x  = (const float*)d_in[0];
    const float* W0 = (const float*)d_in[1];
    const float* b0 = (const float*)d_in[2];
    const float* W1 = (const float*)d_in[3];
    const float* b1 = (const float*)d_in[4];
    const float* W2 = (const float*)d_in[5];
    const float* b2 = (const float*)d_in[6];
    const float* W3 = (const float*)d_in[7];
    const float* b3 = (const float*)d_in[8];
    const float* W4 = (const float*)d_in[9];
    const float* b4 = (const float*)d_in[10];
    unsigned* tab = (unsigned*)d_ws;   // 3*TN*4 = 24 KB scratch

    // PROBE: build launched twice (identical output). dur - 23.9us = build.
    build_table<<<TN / 4, 256, 0, stream>>>(
        W0, b0, W1, b1, W2, b2, W3, b3, W4, b4, tab);
    build_table<<<TN / 4, 256, 0, stream>>>(
        W0, b0, W1, b1, W2, b2, W3, b3, W4, b4, tab);

    unsigned n_out4 = (unsigned)out_size / 4u;   // 3145728
    int blocks = 1536;                           // 6 blocks/CU (24KB LDS)
    apply_s<<<blocks, 256, 0, stream>>>(
        x, tab, (float4*)d_out, n_out4);
}

// Round 16
// 22.566 us; speedup vs baseline: 7.6817x; 1.3089x over previous
//
#include <hip/hip_runtime.h>
#include <hip/hip_fp16.h>
#include <math.h>

// f(x) = tanh-MLP(x), 1->16->32->32->16->3, per scalar element.
// R16 = R10 with build_table stripped of LDS staging: weights read DIRECTLY
// from global inside the layer loops. For fixed k, lanes sub=0..31 read
// W[k*32+sub] = contiguous 128B (coalesced; other half-wave duplicates ->
// broadcast). Loads are act-independent -> hoisted & pipelined under the
// shfl chain; 9KB of weights are L2/LLC-hot after the first blocks.
// Removes: 9 staging rounds + __syncthreads + LDS re-reads (the serial
// prologue that made build ~5.7us of R10's 23.9).
// apply_s: unchanged from R10 (measured ~10.7-12.5us, near 10.6us mem floor).

#define TN 2048
#define XLO (-10.0f)
#define XHI (10.0f)

typedef float f32x4 __attribute__((ext_vector_type(4)));

__device__ __forceinline__ float fast_tanh(float x) {
    float t = __builtin_amdgcn_exp2f(x * 2.885390081777927f);
    return 1.0f - 2.0f * __builtin_amdgcn_rcpf(t + 1.0f);
}

__global__ __launch_bounds__(256) void build_table(
    const float* __restrict__ W0, const float* __restrict__ b0,
    const float* __restrict__ W1, const float* __restrict__ b1,
    const float* __restrict__ W2, const float* __restrict__ b2,
    const float* __restrict__ W3, const float* __restrict__ b3,
    const float* __restrict__ W4, const float* __restrict__ b4,
    unsigned* __restrict__ tab_g)
{
    const int t    = threadIdx.x;
    const int wave = t >> 6;                  // 0..3
    const int half = (t >> 5) & 1;            // 0: point e, 1: point e+1
    const int sub  = t & 31;                  // neuron lane
    const int s16  = (sub < 15) ? sub : 15;
    const int e    = blockIdx.x * 4 + wave;   // entry index, < TN
    const int p    = min(e + half, TN - 1);

    const float h = (XHI - XLO) / (float)(TN - 1);
    const float x = XLO + (float)p * h;

    // L0: 1 -> 16 (coalesced 16-float reads, half-wave broadcast)
    float act = fast_tanh(fmaf(x, W0[s16], b0[s16]));

    // L1: 16 -> 32 (4-way ILP; W loads independent of act -> hoisted)
    {
        float acc0 = b1[sub], acc1 = 0.f, acc2 = 0.f, acc3 = 0.f;
        #pragma unroll
        for (int k = 0; k < 16; k += 4) {
            float a0 = __shfl(act, k + 0, 32);
            float a1 = __shfl(act, k + 1, 32);
            float a2 = __shfl(act, k + 2, 32);
            float a3 = __shfl(act, k + 3, 32);
            acc0 = fmaf(a0, W1[(k + 0) * 32 + sub], acc0);
            acc1 = fmaf(a1, W1[(k + 1) * 32 + sub], acc1);
            acc2 = fmaf(a2, W1[(k + 2) * 32 + sub], acc2);
            acc3 = fmaf(a3, W1[(k + 3) * 32 + sub], acc3);
        }
        act = fast_tanh((acc0 + acc1) + (acc2 + acc3));
    }
    // L2: 32 -> 32
    {
        float acc0 = b2[sub], acc1 = 0.f, acc2 = 0.f, acc3 = 0.f;
        #pragma unroll
        for (int k = 0; k < 32; k += 4) {
            float a0 = __shfl(act, k + 0, 32);
            float a1 = __shfl(act, k + 1, 32);
            float a2 = __shfl(act, k + 2, 32);
            float a3 = __shfl(act, k + 3, 32);
            acc0 = fmaf(a0, W2[(k + 0) * 32 + sub], acc0);
            acc1 = fmaf(a1, W2[(k + 1) * 32 + sub], acc1);
            acc2 = fmaf(a2, W2[(k + 2) * 32 + sub], acc2);
            acc3 = fmaf(a3, W2[(k + 3) * 32 + sub], acc3);
        }
        act = fast_tanh((acc0 + acc1) + (acc2 + acc3));
    }
    // L3: 32 -> 16
    {
        float acc0 = b3[s16], acc1 = 0.f, acc2 = 0.f, acc3 = 0.f;
        #pragma unroll
        for (int k = 0; k < 32; k += 4) {
            float a0 = __shfl(act, k + 0, 32);
            float a1 = __shfl(act, k + 1, 32);
            float a2 = __shfl(act, k + 2, 32);
            float a3 = __shfl(act, k + 3, 32);
            acc0 = fmaf(a0, W3[(k + 0) * 16 + s16], acc0);
            acc1 = fmaf(a1, W3[(k + 1) * 16 + s16], acc1);
            acc2 = fmaf(a2, W3[(k + 2) * 16 + s16], acc2);
            acc3 = fmaf(a3, W3[(k + 3) * 16 + s16], acc3);
        }
        act = fast_tanh((acc0 + acc1) + (acc2 + acc3));
    }
    // L4: 16 -> 3 (uniform addresses -> scalarizable broadcasts)
    float o0 = b4[0], o1 = b4[1], o2 = b4[2];
    #pragma unroll
    for (int k = 0; k < 16; ++k) {
        float ak = __shfl(act, k, 32);
        o0 = fmaf(ak, W4[k * 3 + 0], o0);
        o1 = fmaf(ak, W4[k * 3 + 1], o1);
        o2 = fmaf(ak, W4[k * 3 + 2], o2);
    }
    o0 = fast_tanh(o0); o1 = fast_tanh(o1); o2 = fast_tanh(o2);

    // lane 32 holds point e+1's outputs
    float h0 = __shfl(o0, 32, 64);
    float h1 = __shfl(o1, 32, 64);
    float h2 = __shfl(o2, 32, 64);

    if ((t & 63) == 0) {
        __half2 p0 = __floats2half2_rn(o0, h0);   // .x=f(e), .y=f(e+1)
        __half2 p1 = __floats2half2_rn(o1, h1);
        __half2 p2 = __floats2half2_rn(o2, h2);
        tab_g[         e] = *reinterpret_cast<unsigned*>(&p0);
        tab_g[TN     + e] = *reinterpret_cast<unsigned*>(&p1);
        tab_g[2 * TN + e] = *reinterpret_cast<unsigned*>(&p2);
    }
}

__device__ __forceinline__ void lerp3s(
    const unsigned* __restrict__ t0, const unsigned* __restrict__ t1,
    const unsigned* __restrict__ t2, float inv_h, float x,
    float& y0, float& y1, float& y2)
{
    float xc = fminf(fmaxf(x, XLO), XHI);
    float f  = (xc - XLO) * inv_h;
    int i0 = (int)f;
    i0 = min(i0, TN - 2);
    float fr = f - (float)i0;
    unsigned e0 = t0[i0];
    unsigned e1 = t1[i0];
    unsigned e2 = t2[i0];
    float2 p0 = __half22float2(*reinterpret_cast<__half2*>(&e0));
    float2 p1 = __half22float2(*reinterpret_cast<__half2*>(&e1));
    float2 p2 = __half22float2(*reinterpret_cast<__half2*>(&e2));
    y0 = fmaf(fr, p0.y - p0.x, p0.x);
    y1 = fmaf(fr, p1.y - p1.x, p1.x);
    y2 = fmaf(fr, p2.y - p2.x, p2.x);
}

__global__ __launch_bounds__(256) void apply_s(
    const float* __restrict__ x, const unsigned* __restrict__ tab_g,
    float4* __restrict__ out4, unsigned n_out4)
{
    __shared__ __align__(16) unsigned tab[3 * TN];
    {
        uint4* dst = (uint4*)tab;
        const uint4* src = (const uint4*)tab_g;
        for (int i = threadIdx.x; i < 3 * TN / 4; i += 256) dst[i] = src[i];
    }
    __syncthreads();
    const unsigned* t0 = tab;
    const unsigned* t1 = tab + TN;
    const unsigned* t2 = tab + 2 * TN;

    const float inv_h = (float)(TN - 1) / (XHI - XLO);
    unsigned stride = gridDim.x * 256u;
    for (unsigned g = blockIdx.x * 256u + threadIdx.x; g < n_out4; g += stride) {
        unsigned e = (4u * g) / 3u;
        unsigned r = 4u * g - 3u * e;
        float x0 = x[e];
        float x1 = x[e + 1];
        float s0, s1, s2, s3, s4, s5;
        lerp3s(t0, t1, t2, inv_h, x0, s0, s1, s2);
        lerp3s(t0, t1, t2, inv_h, x1, s3, s4, s5);
        f32x4 o;
        o.x = (r == 0u) ? s0 : ((r == 1u) ? s1 : s2);
        o.y = (r == 0u) ? s1 : ((r == 1u) ? s2 : s3);
        o.z = (r == 0u) ? s2 : ((r == 1u) ? s3 : s4);
        o.w = (r == 0u) ? s3 : ((r == 1u) ? s4 : s5);
        __builtin_nontemporal_store(o, (f32x4*)(out4 + g));
    }
}

extern "C" void kernel_launch(void* const* d_in, const int* in_sizes, int n_in,
                              void* d_out, int out_size, void* d_ws, size_t ws_size,
                              hipStream_t stream) {
    const float* x  = (const float*)d_in[0];
    const float* W0 = (const float*)d_in[1];
    const float* b0 = (const float*)d_in[2];
    const float* W1 = (const float*)d_in[3];
    const float* b1 = (const float*)d_in[4];
    const float* W2 = (const float*)d_in[5];
    const float* b2 = (const float*)d_in[6];
    const float* W3 = (const float*)d_in[7];
    const float* b3 = (const float*)d_in[8];
    const float* W4 = (const float*)d_in[9];
    const float* b4 = (const float*)d_in[10];
    unsigned* tab = (unsigned*)d_ws;   // 3*TN*4 = 24 KB scratch

    build_table<<<TN / 4, 256, 0, stream>>>(
        W0, b0, W1, b1, W2, b2, W3, b3, W4, b4, tab);

    unsigned n_out4 = (unsigned)out_size / 4u;   // 3145728
    int blocks = 1536;                           // 6 blocks/CU (24KB LDS)
    apply_s<<<blocks, 256, 0, stream>>>(
        x, tab, (float4*)d_out, n_out4);
}